// Round 6
// baseline (8249.326 us; speedup 1.0000x reference)
//
#include <hip/hip_runtime.h>
#include <hip/hip_bf16.h>
#include <math.h>

// DiffusionFlow: fused 10-step flow + log-det on MI355X.
// Round 6: r5 structure (32x32x16 MFMA, 8 fat waves x 64 cols, 32 samples/WG)
// + pinned 256-VGPR budget (kills the 918MB/dispatch scratch spill seen at 128),
// + depth-2 B prefetch, + row^(row>>3) swizzle, + vectorized L0/L3 loads.
// Xbuf rows: h 0-31, u0 32-63, u1 64-95; row stride 1024B.
// Swizzle S(r) = ((r ^ (r>>3)) & 7) << 4;  S(r+32) = S(r)^64, S(r+64) = S(r).

typedef float  f32x4  __attribute__((ext_vector_type(4)));
typedef float  f32x16 __attribute__((ext_vector_type(16)));
typedef __bf16 bf16x8 __attribute__((ext_vector_type(8)));

#define SWZ(row) ((((row) ^ ((row) >> 3)) & 7) << 4)

static __device__ __forceinline__ unsigned pkbf2(float a, float b) {
    unsigned short lo = __builtin_bit_cast(unsigned short, __float2bfloat16(a));
    unsigned short hi = __builtin_bit_cast(unsigned short, __float2bfloat16(b));
    return (unsigned)lo | ((unsigned)hi << 16);
}

// ---- pack W (512x512 row-major fp32) -> bf16 A-frag order for 32x32x16 ----
// out[(((c*16+nb)*64)+l)*8+j] = W[nb*32+(l&31)][c*16+(l>>5)*8+j]   (verified r5)
__global__ void pack_w_kernel(const float* __restrict__ W,
                              __hip_bfloat16* __restrict__ out) {
    int i  = blockIdx.x * 512 + threadIdx.x;
    int c  = i >> 13;
    int nb = (i >> 9) & 15;
    int l  = (i >> 3) & 63;
    int j  = i & 7;
    int n  = nb * 32 + (l & 31);
    int k  = c * 16 + ((l >> 5) << 3) + j;
    out[i] = __float2bfloat16(W[n * 512 + k]);
}

// ---- pack W0 cols 0,1 -> contiguous [512][2] fp32 ----
__global__ void pack_w0_kernel(const float* __restrict__ W0,
                               float* __restrict__ w01) {
    int o = threadIdx.x;
    w01[o * 2 + 0] = W0[o * 34 + 0];
    w01[o * 2 + 1] = W0[o * 34 + 1];
}

// ---- c_step[k][o] = b0[o] + W0[o,2:34] . temb(t_k) ----
__global__ void cstep_kernel(const float* __restrict__ W0,
                             const float* __restrict__ b0,
                             float* __restrict__ cst) {
    int k = blockIdx.x;
    int o = threadIdx.x;
    float t = (float)k * 0.1f;
    float acc = b0[o];
    #pragma unroll
    for (int j = 0; j < 16; ++j) {
        float f   = expf(-9.210340371976184f * (float)j / 16.0f);
        float arg = t * f;
        acc += W0[o * 34 + 2 + j]  * sinf(arg);
        acc += W0[o * 34 + 18 + j] * cosf(arg);
    }
    cst[k * 512 + o] = acc;
}

__global__ __launch_bounds__(512)
__attribute__((amdgpu_waves_per_eu(2, 2), amdgpu_num_vgpr(256)))
void flow_kernel(const float* __restrict__ x,
                 const float* __restrict__ w01,
                 const float* __restrict__ cst,
                 const __hip_bfloat16* __restrict__ Wpk1,
                 const __hip_bfloat16* __restrict__ Wpk2,
                 const float* __restrict__ b1,
                 const float* __restrict__ b2,
                 const float* __restrict__ W3,
                 const float* __restrict__ b3v,
                 float* __restrict__ out)
{
    __shared__ __align__(16) __hip_bfloat16 Xbuf[96 * 512];  // 96 KB
    __shared__ float zbuf[32][2];
    __shared__ float ldbuf[32];

    const int tid  = threadIdx.x;
    const int lane = tid & 63;
    const int wid  = tid >> 6;        // 0..7 -> cols [wid*64, wid*64+64)
    const int l31  = lane & 31;
    const int hi   = lane >> 5;       // 0/1
    const int n0w  = wid << 6;
    const int wgs  = blockIdx.x << 5; // 32 samples per WG

    if (tid < 32) {
        zbuf[tid][0] = x[(wgs + tid) * 2 + 0];
        zbuf[tid][1] = x[(wgs + tid) * 2 + 1];
        ldbuf[tid]   = 0.0f;
    }

    // B-frag addressing: rows l31 / l31+32 / l31+64
    const int rowb0 = l31 << 10;
    const int rowb1 = (32 + l31) << 10;
    const int rowb2 = (64 + l31) << 10;
    const int swzB  = SWZ(l31);
    const int hi16  = hi << 4;
    // A-frag: uint4 index = c*1024 + abase (+64 for second n-block)
    const int abase = (wid << 7) + lane;
    const uint4* Wp1 = (const uint4*)Wpk1;
    const uint4* Wp2 = (const uint4*)Wpk2;

    // L0/L3 split: s0 = sample, t16 = 16-way column split
    const int s0   = tid >> 4;
    const int t16  = tid & 15;
    const int swz0 = SWZ(s0);

    __syncthreads();

    #pragma unroll 1
    for (int step = 0; step < 10; ++step) {
        // ---------- layer 0: rank-2 + step-constant, 32 outs/thread ----------
        {
            float z0 = zbuf[s0][0];
            float z1 = zbuf[s0][1];
            const float* cs = cst + (step << 9);
            char* base0 = (char*)Xbuf + (s0 << 10);
            #pragma unroll
            for (int m = 0; m < 4; ++m) {
                int ob = (t16 << 3) + (m << 7);    // element base, 8 outs
                const float4* wv4 = (const float4*)(w01 + (ob << 1));
                const float4* cv4 = (const float4*)(cs + ob);
                float4 wv_0 = wv4[0], wv_1 = wv4[1], wv_2 = wv4[2], wv_3 = wv4[3];
                float4 cv_0 = cv4[0], cv_1 = cv4[1];
                float wq[16] = {wv_0.x, wv_0.y, wv_0.z, wv_0.w,
                                wv_1.x, wv_1.y, wv_1.z, wv_1.w,
                                wv_2.x, wv_2.y, wv_2.z, wv_2.w,
                                wv_3.x, wv_3.y, wv_3.z, wv_3.w};
                float cq[8]  = {cv_0.x, cv_0.y, cv_0.z, cv_0.w,
                                cv_1.x, cv_1.y, cv_1.z, cv_1.w};
                unsigned ph[4], p0[4], p1[4];
                #pragma unroll
                for (int jj = 0; jj < 4; ++jj) {
                    float hv[2], u0v[2], u1v[2];
                    #pragma unroll
                    for (int k = 0; k < 2; ++k) {
                        int j = jj * 2 + k;
                        float w00  = wq[2 * j];
                        float w01v = wq[2 * j + 1];
                        float a   = fmaf(z0, w00, fmaf(z1, w01v, cq[j]));
                        float sig = 1.0f / (1.0f + __expf(-a));
                        float h   = a * sig;
                        float sp  = fmaf(h, 1.0f - sig, sig);   // silu'(a)
                        hv[k]  = h;
                        u0v[k] = sp * w00;
                        u1v[k] = sp * w01v;
                    }
                    ph[jj] = pkbf2(hv[0], hv[1]);
                    p0[jj] = pkbf2(u0v[0], u0v[1]);
                    p1[jj] = pkbf2(u1v[0], u1v[1]);
                }
                int off = (ob << 1) ^ swz0;
                uint4 vph = {ph[0], ph[1], ph[2], ph[3]};
                uint4 vp0 = {p0[0], p0[1], p0[2], p0[3]};
                uint4 vp1 = {p1[0], p1[1], p1[2], p1[3]};
                *(uint4*)(base0 + off)                       = vph;
                *(uint4*)(base0 + (32 << 10) + (off ^ 64))   = vp0;
                *(uint4*)(base0 + (64 << 10) + off)          = vp1;
            }
        }
        __syncthreads();

        // ---------- layers 1,2: D = W @ X^T via 32x32x16 MFMA ----------
        #pragma unroll 1
        for (int layer = 0; layer < 2; ++layer) {
            const uint4* __restrict__ Wp   = layer ? Wp2 : Wp1;
            const float* __restrict__ bias = layer ? b2  : b1;

            // bias loads issued early (L2), consumed in epilogue
            f32x4 bv[2][4];
            #pragma unroll
            for (int nt = 0; nt < 2; ++nt)
                #pragma unroll
                for (int q = 0; q < 4; ++q)
                    bv[nt][q] = *(const f32x4*)(bias + n0w + nt * 32 + q * 8 + hi * 4);

            f32x16 acc[2][3];   // [n-tile of 32][stream]
            #pragma unroll
            for (int nt = 0; nt < 2; ++nt)
                #pragma unroll
                for (int st = 0; st < 3; ++st)
                    acc[nt][st] = (f32x16)(0.0f);

            uint4  a0[2], a1[2];     // A depth-2
            bf16x8 bf0, bf1, bf2;    // B current
            a0[0] = Wp[abase];        a1[0] = Wp[abase + 64];
            a0[1] = Wp[abase + 1024]; a1[1] = Wp[abase + 64 + 1024];
            {
                int t = hi16 ^ swzB;
                bf0 = __builtin_bit_cast(bf16x8, *(const uint4*)((const char*)Xbuf + rowb0 + t));
                bf1 = __builtin_bit_cast(bf16x8, *(const uint4*)((const char*)Xbuf + rowb1 + (t ^ 64)));
                bf2 = __builtin_bit_cast(bf16x8, *(const uint4*)((const char*)Xbuf + rowb2 + t));
            }

            #pragma unroll
            for (int c = 0; c < 32; ++c) {
                uint4 na0, na1;
                if (c + 2 < 32) {
                    na0 = Wp[abase + (c + 2) * 1024];
                    na1 = Wp[abase + 64 + (c + 2) * 1024];
                }
                bf16x8 nb0, nb1, nb2;
                if (c + 1 < 32) {
                    int t = (((c + 1) << 5) | hi16) ^ swzB;
                    nb0 = __builtin_bit_cast(bf16x8, *(const uint4*)((const char*)Xbuf + rowb0 + t));
                    nb1 = __builtin_bit_cast(bf16x8, *(const uint4*)((const char*)Xbuf + rowb1 + (t ^ 64)));
                    nb2 = __builtin_bit_cast(bf16x8, *(const uint4*)((const char*)Xbuf + rowb2 + t));
                }
                bf16x8 av0 = __builtin_bit_cast(bf16x8, a0[c & 1]);
                bf16x8 av1 = __builtin_bit_cast(bf16x8, a1[c & 1]);
                __builtin_amdgcn_s_setprio(1);
                acc[0][0] = __builtin_amdgcn_mfma_f32_32x32x16_bf16(av0, bf0, acc[0][0], 0, 0, 0);
                acc[1][0] = __builtin_amdgcn_mfma_f32_32x32x16_bf16(av1, bf0, acc[1][0], 0, 0, 0);
                acc[0][1] = __builtin_amdgcn_mfma_f32_32x32x16_bf16(av0, bf1, acc[0][1], 0, 0, 0);
                acc[1][1] = __builtin_amdgcn_mfma_f32_32x32x16_bf16(av1, bf1, acc[1][1], 0, 0, 0);
                acc[0][2] = __builtin_amdgcn_mfma_f32_32x32x16_bf16(av0, bf2, acc[0][2], 0, 0, 0);
                acc[1][2] = __builtin_amdgcn_mfma_f32_32x32x16_bf16(av1, bf2, acc[1][2], 0, 0, 0);
                __builtin_amdgcn_s_setprio(0);
                if (c + 2 < 32) { a0[c & 1] = na0; a1[c & 1] = na1; }
                if (c + 1 < 32) { bf0 = nb0; bf1 = nb1; bf2 = nb2; }
            }

            __syncthreads();   // all waves done reading Xbuf before overwrite

            // epilogue: silu + JVP coupling; writes to Xbuf[sample=l31][n]
            {
                char* pb = (char*)Xbuf + (l31 << 10);
                const int swzE = swzB;             // SWZ(l31)
                #pragma unroll
                for (int nt = 0; nt < 2; ++nt) {
                    #pragma unroll
                    for (int q = 0; q < 4; ++q) {
                        unsigned hw[2], u0w[2], u1w[2];
                        #pragma unroll
                        for (int r2 = 0; r2 < 2; ++r2) {
                            float hv[2], u0v[2], u1v[2];
                            #pragma unroll
                            for (int k = 0; k < 2; ++k) {
                                int reg = q * 4 + r2 * 2 + k;
                                float a   = acc[nt][0][reg] + bv[nt][q][r2 * 2 + k];
                                float sig = 1.0f / (1.0f + __expf(-a));
                                float h   = a * sig;
                                float sp  = fmaf(h, 1.0f - sig, sig);
                                hv[k]  = h;
                                u0v[k] = sp * acc[nt][1][reg];
                                u1v[k] = sp * acc[nt][2][reg];
                            }
                            hw[r2]  = pkbf2(hv[0], hv[1]);
                            u0w[r2] = pkbf2(u0v[0], u0v[1]);
                            u1w[r2] = pkbf2(u1v[0], u1v[1]);
                        }
                        int off = ((n0w + nt * 32 + q * 8 + hi * 4) << 1) ^ swzE;
                        uint2 vh = {hw[0], hw[1]};
                        uint2 v0 = {u0w[0], u0w[1]};
                        uint2 v1 = {u1w[0], u1w[1]};
                        *(uint2*)(pb + off)                     = vh;
                        *(uint2*)(pb + (32 << 10) + (off ^ 64)) = v0;
                        *(uint2*)(pb + (64 << 10) + off)        = v1;
                    }
                }
            }
            __syncthreads();
        }

        // ---------- layer 3: six length-512 dots + state update ----------
        {
            float d0 = 0.f, d1 = 0.f, d2 = 0.f, d3 = 0.f, d4 = 0.f, d5 = 0.f;
            #pragma unroll
            for (int p = 0; p < 4; ++p) {
                int eb = (t16 << 3) + (p << 7);    // element base, 8 elems
                const float4* wr0 = (const float4*)(W3 + eb);
                const float4* wr1 = (const float4*)(W3 + 512 + eb);
                float4 wa0 = wr0[0], wa1 = wr0[1];
                float4 wb0 = wr1[0], wb1 = wr1[1];
                float wa[8] = {wa0.x, wa0.y, wa0.z, wa0.w, wa1.x, wa1.y, wa1.z, wa1.w};
                float wb[8] = {wb0.x, wb0.y, wb0.z, wb0.w, wb1.x, wb1.y, wb1.z, wb1.w};
                int offc = (eb << 1);
                #pragma unroll
                for (int st = 0; st < 3; ++st) {
                    int row = s0 + st * 32;
                    int off = (row << 10) + (offc ^ (st == 1 ? (swz0 ^ 64) : swz0));
                    uint4 v = *(const uint4*)((const char*)Xbuf + off);
                    unsigned uu[4] = {v.x, v.y, v.z, v.w};
                    float e[8];
                    #pragma unroll
                    for (int w = 0; w < 4; ++w) {
                        e[2*w]   = __uint_as_float(uu[w] << 16);
                        e[2*w+1] = __uint_as_float(uu[w] & 0xffff0000u);
                    }
                    float sa = 0.f, sb = 0.f;
                    #pragma unroll
                    for (int j = 0; j < 8; ++j) {
                        sa = fmaf(wa[j], e[j], sa);
                        sb = fmaf(wb[j], e[j], sb);
                    }
                    if      (st == 0) { d0 += sa; d1 += sb; }
                    else if (st == 1) { d2 += sa; d3 += sb; }
                    else              { d4 += sa; d5 += sb; }
                }
            }
            #pragma unroll
            for (int m = 1; m < 16; m <<= 1) {
                d0 += __shfl_xor(d0, m);
                d1 += __shfl_xor(d1, m);
                d2 += __shfl_xor(d2, m);
                d3 += __shfl_xor(d3, m);
                d4 += __shfl_xor(d4, m);
                d5 += __shfl_xor(d5, m);
            }
            if (t16 == 0) {
                float v0 = d0 + b3v[0];
                float v1 = d1 + b3v[1];
                float det = (1.0f + 0.1f * d2) * (1.0f + 0.1f * d5)
                          - 0.01f * d4 * d3;
                ldbuf[s0] += logf(fmaxf(fabsf(det), 1e-8f));
                zbuf[s0][0] += 0.1f * v0;
                zbuf[s0][1] += 0.1f * v1;
            }
        }
        __syncthreads();
    }

    if (tid < 32) {
        float z0 = zbuf[tid][0], z1 = zbuf[tid][1];
        out[wgs + tid] = -0.5f * (z0 * z0 + z1 * z1) - 1.8378770664093453f + ldbuf[tid];
    }
}

extern "C" void kernel_launch(void* const* d_in, const int* in_sizes, int n_in,
                              void* d_out, int out_size, void* d_ws, size_t ws_size,
                              hipStream_t stream) {
    const float* x  = (const float*)d_in[0];
    const float* W0 = (const float*)d_in[1];   // (512, 34)
    const float* b0 = (const float*)d_in[2];
    const float* W1 = (const float*)d_in[3];   // (512, 512)
    const float* b1 = (const float*)d_in[4];
    const float* W2 = (const float*)d_in[5];
    const float* b2 = (const float*)d_in[6];
    const float* W3 = (const float*)d_in[7];   // (2, 512)
    const float* b3 = (const float*)d_in[8];
    float* out = (float*)d_out;

    char* ws = (char*)d_ws;
    __hip_bfloat16* wpk1 = (__hip_bfloat16*)ws;                  // 512 KB
    __hip_bfloat16* wpk2 = (__hip_bfloat16*)(ws + (512u << 10)); // 512 KB
    float*          cstp = (float*)(ws + (1024u << 10));         // 20 KB
    float*          w01p = (float*)(ws + (1044u << 10));         // 4 KB

    pack_w_kernel<<<512, 512, 0, stream>>>(W1, wpk1);
    pack_w_kernel<<<512, 512, 0, stream>>>(W2, wpk2);
    cstep_kernel<<<10, 512, 0, stream>>>(W0, b0, cstp);
    pack_w0_kernel<<<1, 512, 0, stream>>>(W0, w01p);
    flow_kernel<<<131072 / 32, 512, 0, stream>>>(x, w01p, cstp, wpk1, wpk2,
                                                 b1, b2, W3, b3, out);
}

// Round 7
// 6744.086 us; speedup vs baseline: 1.2232x; 1.2232x over previous
//
#include <hip/hip_runtime.h>
#include <hip/hip_bf16.h>
#include <math.h>

// DiffusionFlow: fused 10-step flow + log-det on MI355X.
// Round 7: fit the empirically-fixed 128-VGPR budget instead of fighting it.
// 16 samples/WG, M=48 rows (h 0-15, u0 16-31, u1 32-47), 512 thr / 8 waves,
// wave owns 64 cols (4 n-tiles of 16), 16x16x32 MFMA (frag paths verified r2-r4).
// acc = 4x3 f32x4 = 48 regs -> live set ~105 <= 128: no scratch spill.
// Xbuf 48 KB -> 2 WGs/CU co-resident: K-loop of one WG hides serial phases of the other.
// Swizzle: byteoff = (col*2) ^ ((row&7)<<4) at every Xbuf access site.

typedef float  f32x4  __attribute__((ext_vector_type(4)));
typedef __bf16 bf16x8 __attribute__((ext_vector_type(8)));

static __device__ __forceinline__ unsigned pkbf2(float a, float b) {
    unsigned short lo = __builtin_bit_cast(unsigned short, __float2bfloat16(a));
    unsigned short hi = __builtin_bit_cast(unsigned short, __float2bfloat16(b));
    return (unsigned)lo | ((unsigned)hi << 16);
}

// ---- pack W (512x512 row-major fp32) -> bf16 [c][n][32], c = k-chunk of 32 ----
// out[(c*512 + n)*32 + kk] = W[n][c*32 + kk]   (A-frag order, verified r2-r4)
__global__ void pack_w_kernel(const float* __restrict__ W,
                              __hip_bfloat16* __restrict__ out) {
    int i  = blockIdx.x * 512 + threadIdx.x;
    int c  = i >> 14;
    int n  = (i & 16383) >> 5;
    int kk = i & 31;
    out[i] = __float2bfloat16(W[n * 512 + (c << 5) + kk]);
}

// ---- pack W0 cols 0,1 -> contiguous [512][2] fp32 ----
__global__ void pack_w0_kernel(const float* __restrict__ W0,
                               float* __restrict__ w01) {
    int o = threadIdx.x;
    w01[o * 2 + 0] = W0[o * 34 + 0];
    w01[o * 2 + 1] = W0[o * 34 + 1];
}

// ---- c_step[k][o] = b0[o] + W0[o,2:34] . temb(t_k) ----
__global__ void cstep_kernel(const float* __restrict__ W0,
                             const float* __restrict__ b0,
                             float* __restrict__ cst) {
    int k = blockIdx.x;
    int o = threadIdx.x;
    float t = (float)k * 0.1f;
    float acc = b0[o];
    #pragma unroll
    for (int j = 0; j < 16; ++j) {
        float f   = expf(-9.210340371976184f * (float)j / 16.0f);
        float arg = t * f;
        acc += W0[o * 34 + 2 + j]  * sinf(arg);
        acc += W0[o * 34 + 18 + j] * cosf(arg);
    }
    cst[k * 512 + o] = acc;
}

__global__ __launch_bounds__(512)
void flow_kernel(const float* __restrict__ x,
                 const float* __restrict__ w01,
                 const float* __restrict__ cst,
                 const __hip_bfloat16* __restrict__ Wpk1,
                 const __hip_bfloat16* __restrict__ Wpk2,
                 const float* __restrict__ b1,
                 const float* __restrict__ b2,
                 const float* __restrict__ W3,
                 const float* __restrict__ b3v,
                 float* __restrict__ out)
{
    __shared__ __align__(16) __hip_bfloat16 Xbuf[48 * 512];  // 48 KB
    __shared__ float zbuf[16][2];
    __shared__ float ldbuf[16];

    const int tid  = threadIdx.x;
    const int lane = tid & 63;
    const int wid  = tid >> 6;        // 0..7 -> cols [wid*64, wid*64+64)
    const int l15  = lane & 15;
    const int lq   = lane >> 4;       // 0..3
    const int n0w  = wid << 6;
    const int wgs  = blockIdx.x << 4; // 16 samples per WG

    if (tid < 16) {
        zbuf[tid][0] = x[(wgs + tid) * 2 + 0];
        zbuf[tid][1] = x[(wgs + tid) * 2 + 1];
        ldbuf[tid]   = 0.0f;
    }

    // B-frag (X from LDS): rows l15 / 16+l15 / 32+l15, same swizzle for all three
    const int rowb0 = l15 << 10;
    const int rowb1 = (16 + l15) << 10;
    const int rowb2 = (32 + l15) << 10;
    const int swzB  = (l15 & 7) << 4;
    const int lq16  = lq << 4;
    // A-frag: uint4 index = c*2048 + abase + nt*64
    const int abase = ((n0w + l15) << 2) + lq;
    const uint4* Wp1 = (const uint4*)Wpk1;
    const uint4* Wp2 = (const uint4*)Wpk2;

    // L0/L3 split: s0 = sample (tid>>5), t32 = 32-way column split
    const int s0   = tid >> 5;
    const int t32  = tid & 31;
    const int swz0 = (s0 & 7) << 4;

    __syncthreads();

    #pragma unroll 1
    for (int step = 0; step < 10; ++step) {
        // ---------- layer 0: rank-2 + step-constant, 16 outs/thread ----------
        {
            float z0 = zbuf[s0][0];
            float z1 = zbuf[s0][1];
            const float* cs = cst + (step << 9);
            char* base0 = (char*)Xbuf + (s0 << 10);
            #pragma unroll
            for (int m = 0; m < 2; ++m) {
                int ob = (t32 << 4) + (m << 3);    // element base, 8 outs
                const float4* wv4 = (const float4*)(w01 + (ob << 1));
                const float4* cv4 = (const float4*)(cs + ob);
                float4 wv_0 = wv4[0], wv_1 = wv4[1], wv_2 = wv4[2], wv_3 = wv4[3];
                float4 cv_0 = cv4[0], cv_1 = cv4[1];
                float wq[16] = {wv_0.x, wv_0.y, wv_0.z, wv_0.w,
                                wv_1.x, wv_1.y, wv_1.z, wv_1.w,
                                wv_2.x, wv_2.y, wv_2.z, wv_2.w,
                                wv_3.x, wv_3.y, wv_3.z, wv_3.w};
                float cq[8]  = {cv_0.x, cv_0.y, cv_0.z, cv_0.w,
                                cv_1.x, cv_1.y, cv_1.z, cv_1.w};
                unsigned ph[4], p0[4], p1[4];
                #pragma unroll
                for (int jj = 0; jj < 4; ++jj) {
                    float hv[2], u0v[2], u1v[2];
                    #pragma unroll
                    for (int k = 0; k < 2; ++k) {
                        int j = jj * 2 + k;
                        float w00  = wq[2 * j];
                        float w01v = wq[2 * j + 1];
                        float a   = fmaf(z0, w00, fmaf(z1, w01v, cq[j]));
                        float sig = 1.0f / (1.0f + __expf(-a));
                        float h   = a * sig;
                        float sp  = fmaf(h, 1.0f - sig, sig);   // silu'(a)
                        hv[k]  = h;
                        u0v[k] = sp * w00;
                        u1v[k] = sp * w01v;
                    }
                    ph[jj] = pkbf2(hv[0], hv[1]);
                    p0[jj] = pkbf2(u0v[0], u0v[1]);
                    p1[jj] = pkbf2(u1v[0], u1v[1]);
                }
                int off = (ob << 1) ^ swz0;
                uint4 vph = {ph[0], ph[1], ph[2], ph[3]};
                uint4 vp0 = {p0[0], p0[1], p0[2], p0[3]};
                uint4 vp1 = {p1[0], p1[1], p1[2], p1[3]};
                *(uint4*)(base0 + off)              = vph;
                *(uint4*)(base0 + (16 << 10) + off) = vp0;
                *(uint4*)(base0 + (32 << 10) + off) = vp1;
            }
        }
        __syncthreads();

        // ---------- layers 1,2: D = W @ X^T, 512x48x512, 16x16x32 MFMA ----------
        #pragma unroll 1
        for (int layer = 0; layer < 2; ++layer) {
            const uint4* __restrict__ Wp   = layer ? Wp2 : Wp1;
            const float* __restrict__ bias = layer ? b2  : b1;

            f32x4 acc[4][3];   // [n-tile][stream]
            #pragma unroll
            for (int nt = 0; nt < 4; ++nt)
                #pragma unroll
                for (int mt = 0; mt < 3; ++mt)
                    acc[nt][mt] = (f32x4){0.f, 0.f, 0.f, 0.f};

            uint4 Af[2][4];    // W frags, depth-2 rotation
            auto loada = [&](uint4 (&dst)[4], int c) {
                const uint4* p = Wp + c * 2048 + abase;
                dst[0] = p[0]; dst[1] = p[64]; dst[2] = p[128]; dst[3] = p[192];
            };
            loada(Af[0], 0);

            #pragma unroll
            for (int c = 0; c < 16; ++c) {
                if (c + 1 < 16) loada(Af[(c + 1) & 1], c + 1);
                bf16x8 Bf[3];
                int kx = ((c << 6) | lq16) ^ swzB;
                Bf[0] = __builtin_bit_cast(bf16x8, *(const uint4*)((const char*)Xbuf + rowb0 + kx));
                Bf[1] = __builtin_bit_cast(bf16x8, *(const uint4*)((const char*)Xbuf + rowb1 + kx));
                Bf[2] = __builtin_bit_cast(bf16x8, *(const uint4*)((const char*)Xbuf + rowb2 + kx));
                __builtin_amdgcn_s_setprio(1);
                #pragma unroll
                for (int mt = 0; mt < 3; ++mt)
                    #pragma unroll
                    for (int nt = 0; nt < 4; ++nt)
                        acc[nt][mt] = __builtin_amdgcn_mfma_f32_16x16x32_bf16(
                            __builtin_bit_cast(bf16x8, Af[c & 1][nt]),
                            Bf[mt], acc[nt][mt], 0, 0, 0);
                __builtin_amdgcn_s_setprio(0);
            }

            // bias after K-loop (keeps in-loop live set minimal)
            f32x4 bv[4];
            #pragma unroll
            for (int nt = 0; nt < 4; ++nt)
                bv[nt] = *(const f32x4*)(bias + n0w + nt * 16 + (lq << 2));

            __syncthreads();   // all waves done reading Xbuf before overwrite

            // epilogue: silu + JVP coupling; 12 uint2 LDS writes/thread
            {
                char* pbase = (char*)Xbuf + (l15 << 10);   // D col = sample = l15
                #pragma unroll
                for (int nt = 0; nt < 4; ++nt) {
                    unsigned hw[2], u0w[2], u1w[2];
                    #pragma unroll
                    for (int r2 = 0; r2 < 2; ++r2) {
                        float hv[2], u0v[2], u1v[2];
                        #pragma unroll
                        for (int k = 0; k < 2; ++k) {
                            int r = r2 * 2 + k;            // D row = n = n0w+nt*16+lq*4+r
                            float a   = acc[nt][0][r] + bv[nt][r];
                            float sig = 1.0f / (1.0f + __expf(-a));
                            float h   = a * sig;
                            float sp  = fmaf(h, 1.0f - sig, sig);
                            hv[k]  = h;
                            u0v[k] = sp * acc[nt][1][r];
                            u1v[k] = sp * acc[nt][2][r];
                        }
                        hw[r2]  = pkbf2(hv[0], hv[1]);
                        u0w[r2] = pkbf2(u0v[0], u0v[1]);
                        u1w[r2] = pkbf2(u1v[0], u1v[1]);
                    }
                    int off = ((n0w + nt * 16 + (lq << 2)) << 1) ^ swzB;
                    uint2 vh = {hw[0], hw[1]};
                    uint2 v0 = {u0w[0], u0w[1]};
                    uint2 v1 = {u1w[0], u1w[1]};
                    *(uint2*)(pbase + off)              = vh;
                    *(uint2*)(pbase + (16 << 10) + off) = v0;
                    *(uint2*)(pbase + (32 << 10) + off) = v1;
                }
            }
            __syncthreads();
        }

        // ---------- layer 3: six length-512 dots + state update ----------
        {
            float d0 = 0.f, d1 = 0.f, d2 = 0.f, d3 = 0.f, d4 = 0.f, d5 = 0.f;
            int eb = t32 << 4;                 // 16 elems per thread
            const float4* wr0 = (const float4*)(W3 + eb);
            const float4* wr1 = (const float4*)(W3 + 512 + eb);
            float4 wa0 = wr0[0], wa1 = wr0[1], wa2 = wr0[2], wa3 = wr0[3];
            float4 wb0 = wr1[0], wb1 = wr1[1], wb2 = wr1[2], wb3 = wr1[3];
            float wa[16] = {wa0.x, wa0.y, wa0.z, wa0.w, wa1.x, wa1.y, wa1.z, wa1.w,
                            wa2.x, wa2.y, wa2.z, wa2.w, wa3.x, wa3.y, wa3.z, wa3.w};
            float wb[16] = {wb0.x, wb0.y, wb0.z, wb0.w, wb1.x, wb1.y, wb1.z, wb1.w,
                            wb2.x, wb2.y, wb2.z, wb2.w, wb3.x, wb3.y, wb3.z, wb3.w};
            #pragma unroll
            for (int st = 0; st < 3; ++st) {
                int row = s0 + st * 16;
                const char* rb = (const char*)Xbuf + (row << 10);
                float e[16];
                #pragma unroll
                for (int q = 0; q < 2; ++q) {
                    int off = (((t32 << 5) + (q << 4))) ^ swz0;
                    uint4 v = *(const uint4*)(rb + off);
                    unsigned uu[4] = {v.x, v.y, v.z, v.w};
                    #pragma unroll
                    for (int w = 0; w < 4; ++w) {
                        e[q*8 + 2*w]   = __uint_as_float(uu[w] << 16);
                        e[q*8 + 2*w+1] = __uint_as_float(uu[w] & 0xffff0000u);
                    }
                }
                float sa = 0.f, sb = 0.f;
                #pragma unroll
                for (int j = 0; j < 16; ++j) {
                    sa = fmaf(wa[j], e[j], sa);
                    sb = fmaf(wb[j], e[j], sb);
                }
                if      (st == 0) { d0 = sa; d1 = sb; }
                else if (st == 1) { d2 = sa; d3 = sb; }
                else              { d4 = sa; d5 = sb; }
            }
            #pragma unroll
            for (int m = 1; m < 32; m <<= 1) {
                d0 += __shfl_xor(d0, m);
                d1 += __shfl_xor(d1, m);
                d2 += __shfl_xor(d2, m);
                d3 += __shfl_xor(d3, m);
                d4 += __shfl_xor(d4, m);
                d5 += __shfl_xor(d5, m);
            }
            if (t32 == 0) {
                float v0 = d0 + b3v[0];
                float v1 = d1 + b3v[1];
                float det = (1.0f + 0.1f * d2) * (1.0f + 0.1f * d5)
                          - 0.01f * d4 * d3;
                ldbuf[s0] += logf(fmaxf(fabsf(det), 1e-8f));
                zbuf[s0][0] += 0.1f * v0;
                zbuf[s0][1] += 0.1f * v1;
            }
        }
        __syncthreads();
    }

    if (tid < 16) {
        float z0 = zbuf[tid][0], z1 = zbuf[tid][1];
        out[wgs + tid] = -0.5f * (z0 * z0 + z1 * z1) - 1.8378770664093453f + ldbuf[tid];
    }
}

extern "C" void kernel_launch(void* const* d_in, const int* in_sizes, int n_in,
                              void* d_out, int out_size, void* d_ws, size_t ws_size,
                              hipStream_t stream) {
    const float* x  = (const float*)d_in[0];
    const float* W0 = (const float*)d_in[1];   // (512, 34)
    const float* b0 = (const float*)d_in[2];
    const float* W1 = (const float*)d_in[3];   // (512, 512)
    const float* b1 = (const float*)d_in[4];
    const float* W2 = (const float*)d_in[5];
    const float* b2 = (const float*)d_in[6];
    const float* W3 = (const float*)d_in[7];   // (2, 512)
    const float* b3 = (const float*)d_in[8];
    float* out = (float*)d_out;

    char* ws = (char*)d_ws;
    __hip_bfloat16* wpk1 = (__hip_bfloat16*)ws;                  // 512 KB
    __hip_bfloat16* wpk2 = (__hip_bfloat16*)(ws + (512u << 10)); // 512 KB
    float*          cstp = (float*)(ws + (1024u << 10));         // 20 KB
    float*          w01p = (float*)(ws + (1044u << 10));         // 4 KB

    pack_w_kernel<<<512, 512, 0, stream>>>(W1, wpk1);
    pack_w_kernel<<<512, 512, 0, stream>>>(W2, wpk2);
    cstep_kernel<<<10, 512, 0, stream>>>(W0, b0, cstp);
    pack_w0_kernel<<<1, 512, 0, stream>>>(W0, w01p);
    flow_kernel<<<131072 / 16, 512, 0, stream>>>(x, w01p, cstp, wpk1, wpk2,
                                                 b1, b2, W3, b3, out);
}

// Round 8
// 6549.227 us; speedup vs baseline: 1.2596x; 1.0298x over previous
//
#include <hip/hip_runtime.h>
#include <hip/hip_bf16.h>
#include <math.h>

// DiffusionFlow: fused 10-step flow + log-det on MI355X.
// Round 8: r7 structure (16 samples/WG, M=48, 512 thr / 8 waves, 16x16x32)
// + inline-asm MFMA with "+v" accumulators: keeps C/D in ARCH VGPRs (gfx950
//   unified file), eliminating the arch+AGPR split (120+48>128) that blocked
//   the 2nd workgroup per CU in r7.
// + waves_per_eu(4,4): budget 128 total, live ~112 -> no spill, 2 WGs/CU.
// Xbuf 48 KB; swizzle byteoff = (col*2) ^ ((row&7)<<4) at every access site.

typedef float  f32x4  __attribute__((ext_vector_type(4)));
typedef __bf16 bf16x8 __attribute__((ext_vector_type(8)));

static __device__ __forceinline__ unsigned pkbf2(float a, float b) {
    unsigned short lo = __builtin_bit_cast(unsigned short, __float2bfloat16(a));
    unsigned short hi = __builtin_bit_cast(unsigned short, __float2bfloat16(b));
    return (unsigned)lo | ((unsigned)hi << 16);
}

static __device__ __forceinline__ void mfma_v(f32x4& acc, bf16x8 a, bf16x8 b) {
    // VGPR-form MFMA: forces D/C into arch VGPRs (no AGPR split).
    asm("v_mfma_f32_16x16x32_bf16 %0, %1, %2, %0" : "+v"(acc) : "v"(a), "v"(b));
}

// ---- pack W (512x512 row-major fp32) -> bf16 [c][n][32], c = k-chunk of 32 ----
__global__ void pack_w_kernel(const float* __restrict__ W,
                              __hip_bfloat16* __restrict__ out) {
    int i  = blockIdx.x * 512 + threadIdx.x;
    int c  = i >> 14;
    int n  = (i & 16383) >> 5;
    int kk = i & 31;
    out[i] = __float2bfloat16(W[n * 512 + (c << 5) + kk]);
}

// ---- pack W0 cols 0,1 -> contiguous [512][2] fp32 ----
__global__ void pack_w0_kernel(const float* __restrict__ W0,
                               float* __restrict__ w01) {
    int o = threadIdx.x;
    w01[o * 2 + 0] = W0[o * 34 + 0];
    w01[o * 2 + 1] = W0[o * 34 + 1];
}

// ---- c_step[k][o] = b0[o] + W0[o,2:34] . temb(t_k) ----
__global__ void cstep_kernel(const float* __restrict__ W0,
                             const float* __restrict__ b0,
                             float* __restrict__ cst) {
    int k = blockIdx.x;
    int o = threadIdx.x;
    float t = (float)k * 0.1f;
    float acc = b0[o];
    #pragma unroll
    for (int j = 0; j < 16; ++j) {
        float f   = expf(-9.210340371976184f * (float)j / 16.0f);
        float arg = t * f;
        acc += W0[o * 34 + 2 + j]  * sinf(arg);
        acc += W0[o * 34 + 18 + j] * cosf(arg);
    }
    cst[k * 512 + o] = acc;
}

__global__ __launch_bounds__(512)
__attribute__((amdgpu_waves_per_eu(4, 4)))
void flow_kernel(const float* __restrict__ x,
                 const float* __restrict__ w01,
                 const float* __restrict__ cst,
                 const __hip_bfloat16* __restrict__ Wpk1,
                 const __hip_bfloat16* __restrict__ Wpk2,
                 const float* __restrict__ b1,
                 const float* __restrict__ b2,
                 const float* __restrict__ W3,
                 const float* __restrict__ b3v,
                 float* __restrict__ out)
{
    __shared__ __align__(16) __hip_bfloat16 Xbuf[48 * 512];  // 48 KB
    __shared__ float zbuf[16][2];
    __shared__ float ldbuf[16];

    const int tid  = threadIdx.x;
    const int lane = tid & 63;
    const int wid  = tid >> 6;        // 0..7 -> cols [wid*64, wid*64+64)
    const int l15  = lane & 15;
    const int lq   = lane >> 4;       // 0..3
    const int n0w  = wid << 6;
    const int wgs  = blockIdx.x << 4; // 16 samples per WG

    if (tid < 16) {
        zbuf[tid][0] = x[(wgs + tid) * 2 + 0];
        zbuf[tid][1] = x[(wgs + tid) * 2 + 1];
        ldbuf[tid]   = 0.0f;
    }

    // B-frag (X from LDS): rows l15 / 16+l15 / 32+l15, same swizzle for all three
    const int rowb0 = l15 << 10;
    const int rowb1 = (16 + l15) << 10;
    const int rowb2 = (32 + l15) << 10;
    const int swzB  = (l15 & 7) << 4;
    const int lq16  = lq << 4;
    // A-frag: uint4 index = c*2048 + abase + nt*64
    const int abase = ((n0w + l15) << 2) + lq;
    const uint4* Wp1 = (const uint4*)Wpk1;
    const uint4* Wp2 = (const uint4*)Wpk2;

    // L0/L3 split: s0 = sample (tid>>5), t32 = 32-way column split
    const int s0   = tid >> 5;
    const int t32  = tid & 31;
    const int swz0 = (s0 & 7) << 4;

    __syncthreads();

    #pragma unroll 1
    for (int step = 0; step < 10; ++step) {
        // ---------- layer 0: rank-2 + step-constant, 16 outs/thread ----------
        {
            float z0 = zbuf[s0][0];
            float z1 = zbuf[s0][1];
            const float* cs = cst + (step << 9);
            char* base0 = (char*)Xbuf + (s0 << 10);
            #pragma unroll
            for (int m = 0; m < 2; ++m) {
                int ob = (t32 << 4) + (m << 3);    // element base, 8 outs
                const float4* wv4 = (const float4*)(w01 + (ob << 1));
                const float4* cv4 = (const float4*)(cs + ob);
                float4 wv_0 = wv4[0], wv_1 = wv4[1], wv_2 = wv4[2], wv_3 = wv4[3];
                float4 cv_0 = cv4[0], cv_1 = cv4[1];
                float wq[16] = {wv_0.x, wv_0.y, wv_0.z, wv_0.w,
                                wv_1.x, wv_1.y, wv_1.z, wv_1.w,
                                wv_2.x, wv_2.y, wv_2.z, wv_2.w,
                                wv_3.x, wv_3.y, wv_3.z, wv_3.w};
                float cq[8]  = {cv_0.x, cv_0.y, cv_0.z, cv_0.w,
                                cv_1.x, cv_1.y, cv_1.z, cv_1.w};
                unsigned ph[4], p0[4], p1[4];
                #pragma unroll
                for (int jj = 0; jj < 4; ++jj) {
                    float hv[2], u0v[2], u1v[2];
                    #pragma unroll
                    for (int k = 0; k < 2; ++k) {
                        int j = jj * 2 + k;
                        float w00  = wq[2 * j];
                        float w01v = wq[2 * j + 1];
                        float a   = fmaf(z0, w00, fmaf(z1, w01v, cq[j]));
                        float sig = 1.0f / (1.0f + __expf(-a));
                        float h   = a * sig;
                        float sp  = fmaf(h, 1.0f - sig, sig);   // silu'(a)
                        hv[k]  = h;
                        u0v[k] = sp * w00;
                        u1v[k] = sp * w01v;
                    }
                    ph[jj] = pkbf2(hv[0], hv[1]);
                    p0[jj] = pkbf2(u0v[0], u0v[1]);
                    p1[jj] = pkbf2(u1v[0], u1v[1]);
                }
                int off = (ob << 1) ^ swz0;
                uint4 vph = {ph[0], ph[1], ph[2], ph[3]};
                uint4 vp0 = {p0[0], p0[1], p0[2], p0[3]};
                uint4 vp1 = {p1[0], p1[1], p1[2], p1[3]};
                *(uint4*)(base0 + off)              = vph;
                *(uint4*)(base0 + (16 << 10) + off) = vp0;
                *(uint4*)(base0 + (32 << 10) + off) = vp1;
            }
        }
        __syncthreads();

        // ---------- layers 1,2: D = W @ X^T, 512x48x512, 16x16x32 MFMA ----------
        #pragma unroll 1
        for (int layer = 0; layer < 2; ++layer) {
            const uint4* __restrict__ Wp   = layer ? Wp2 : Wp1;
            const float* __restrict__ bias = layer ? b2  : b1;

            f32x4 acc[4][3];   // [n-tile][stream] -- arch VGPRs via asm MFMA
            #pragma unroll
            for (int nt = 0; nt < 4; ++nt)
                #pragma unroll
                for (int mt = 0; mt < 3; ++mt)
                    acc[nt][mt] = (f32x4){0.f, 0.f, 0.f, 0.f};

            uint4 Af[2][4];    // W frags, depth-2 rotation
            auto loada = [&](uint4 (&dst)[4], int c) {
                const uint4* p = Wp + c * 2048 + abase;
                dst[0] = p[0]; dst[1] = p[64]; dst[2] = p[128]; dst[3] = p[192];
            };
            loada(Af[0], 0);

            #pragma unroll
            for (int c = 0; c < 16; ++c) {
                if (c + 1 < 16) loada(Af[(c + 1) & 1], c + 1);
                bf16x8 Bf[3];
                int kx = ((c << 6) | lq16) ^ swzB;
                Bf[0] = __builtin_bit_cast(bf16x8, *(const uint4*)((const char*)Xbuf + rowb0 + kx));
                Bf[1] = __builtin_bit_cast(bf16x8, *(const uint4*)((const char*)Xbuf + rowb1 + kx));
                Bf[2] = __builtin_bit_cast(bf16x8, *(const uint4*)((const char*)Xbuf + rowb2 + kx));
                __builtin_amdgcn_s_setprio(1);
                #pragma unroll
                for (int mt = 0; mt < 3; ++mt)
                    #pragma unroll
                    for (int nt = 0; nt < 4; ++nt)
                        mfma_v(acc[nt][mt],
                               __builtin_bit_cast(bf16x8, Af[c & 1][nt]), Bf[mt]);
                __builtin_amdgcn_s_setprio(0);
            }

            // MFMA->VALU hazard guard (compiler can't model asm MFMA latency)
            asm volatile("s_nop 7\n\ts_nop 7");

            f32x4 bv[4];
            #pragma unroll
            for (int nt = 0; nt < 4; ++nt)
                bv[nt] = *(const f32x4*)(bias + n0w + nt * 16 + (lq << 2));

            __syncthreads();   // all waves done reading Xbuf before overwrite

            // epilogue: silu + JVP coupling; 12 uint2 LDS writes/thread
            {
                char* pbase = (char*)Xbuf + (l15 << 10);   // D col = sample = l15
                #pragma unroll
                for (int nt = 0; nt < 4; ++nt) {
                    unsigned hw[2], u0w[2], u1w[2];
                    #pragma unroll
                    for (int r2 = 0; r2 < 2; ++r2) {
                        float hv[2], u0v[2], u1v[2];
                        #pragma unroll
                        for (int k = 0; k < 2; ++k) {
                            int r = r2 * 2 + k;            // D row = n = n0w+nt*16+lq*4+r
                            float a   = acc[nt][0][r] + bv[nt][r];
                            float sig = 1.0f / (1.0f + __expf(-a));
                            float h   = a * sig;
                            float sp  = fmaf(h, 1.0f - sig, sig);
                            hv[k]  = h;
                            u0v[k] = sp * acc[nt][1][r];
                            u1v[k] = sp * acc[nt][2][r];
                        }
                        hw[r2]  = pkbf2(hv[0], hv[1]);
                        u0w[r2] = pkbf2(u0v[0], u0v[1]);
                        u1w[r2] = pkbf2(u1v[0], u1v[1]);
                    }
                    int off = ((n0w + nt * 16 + (lq << 2)) << 1) ^ swzB;
                    uint2 vh = {hw[0], hw[1]};
                    uint2 v0 = {u0w[0], u0w[1]};
                    uint2 v1 = {u1w[0], u1w[1]};
                    *(uint2*)(pbase + off)              = vh;
                    *(uint2*)(pbase + (16 << 10) + off) = v0;
                    *(uint2*)(pbase + (32 << 10) + off) = v1;
                }
            }
            __syncthreads();
        }

        // ---------- layer 3: six length-512 dots + state update ----------
        {
            float d0 = 0.f, d1 = 0.f, d2 = 0.f, d3 = 0.f, d4 = 0.f, d5 = 0.f;
            int eb = t32 << 4;                 // 16 elems per thread
            const float4* wr0 = (const float4*)(W3 + eb);
            const float4* wr1 = (const float4*)(W3 + 512 + eb);
            float4 wa0 = wr0[0], wa1 = wr0[1], wa2 = wr0[2], wa3 = wr0[3];
            float4 wb0 = wr1[0], wb1 = wr1[1], wb2 = wr1[2], wb3 = wr1[3];
            float wa[16] = {wa0.x, wa0.y, wa0.z, wa0.w, wa1.x, wa1.y, wa1.z, wa1.w,
                            wa2.x, wa2.y, wa2.z, wa2.w, wa3.x, wa3.y, wa3.z, wa3.w};
            float wb[16] = {wb0.x, wb0.y, wb0.z, wb0.w, wb1.x, wb1.y, wb1.z, wb1.w,
                            wb2.x, wb2.y, wb2.z, wb2.w, wb3.x, wb3.y, wb3.z, wb3.w};
            #pragma unroll
            for (int st = 0; st < 3; ++st) {
                int row = s0 + st * 16;
                const char* rb = (const char*)Xbuf + (row << 10);
                float e[16];
                #pragma unroll
                for (int q = 0; q < 2; ++q) {
                    int off = (((t32 << 5) + (q << 4))) ^ swz0;
                    uint4 v = *(const uint4*)(rb + off);
                    unsigned uu[4] = {v.x, v.y, v.z, v.w};
                    #pragma unroll
                    for (int w = 0; w < 4; ++w) {
                        e[q*8 + 2*w]   = __uint_as_float(uu[w] << 16);
                        e[q*8 + 2*w+1] = __uint_as_float(uu[w] & 0xffff0000u);
                    }
                }
                float sa = 0.f, sb = 0.f;
                #pragma unroll
                for (int j = 0; j < 16; ++j) {
                    sa = fmaf(wa[j], e[j], sa);
                    sb = fmaf(wb[j], e[j], sb);
                }
                if      (st == 0) { d0 = sa; d1 = sb; }
                else if (st == 1) { d2 = sa; d3 = sb; }
                else              { d4 = sa; d5 = sb; }
            }
            #pragma unroll
            for (int m = 1; m < 32; m <<= 1) {
                d0 += __shfl_xor(d0, m);
                d1 += __shfl_xor(d1, m);
                d2 += __shfl_xor(d2, m);
                d3 += __shfl_xor(d3, m);
                d4 += __shfl_xor(d4, m);
                d5 += __shfl_xor(d5, m);
            }
            if (t32 == 0) {
                float v0 = d0 + b3v[0];
                float v1 = d1 + b3v[1];
                float det = (1.0f + 0.1f * d2) * (1.0f + 0.1f * d5)
                          - 0.01f * d4 * d3;
                ldbuf[s0] += logf(fmaxf(fabsf(det), 1e-8f));
                zbuf[s0][0] += 0.1f * v0;
                zbuf[s0][1] += 0.1f * v1;
            }
        }
        __syncthreads();
    }

    if (tid < 16) {
        float z0 = zbuf[tid][0], z1 = zbuf[tid][1];
        out[wgs + tid] = -0.5f * (z0 * z0 + z1 * z1) - 1.8378770664093453f + ldbuf[tid];
    }
}

extern "C" void kernel_launch(void* const* d_in, const int* in_sizes, int n_in,
                              void* d_out, int out_size, void* d_ws, size_t ws_size,
                              hipStream_t stream) {
    const float* x  = (const float*)d_in[0];
    const float* W0 = (const float*)d_in[1];   // (512, 34)
    const float* b0 = (const float*)d_in[2];
    const float* W1 = (const float*)d_in[3];   // (512, 512)
    const float* b1 = (const float*)d_in[4];
    const float* W2 = (const float*)d_in[5];
    const float* b2 = (const float*)d_in[6];
    const float* W3 = (const float*)d_in[7];   // (2, 512)
    const float* b3 = (const float*)d_in[8];
    float* out = (float*)d_out;

    char* ws = (char*)d_ws;
    __hip_bfloat16* wpk1 = (__hip_bfloat16*)ws;                  // 512 KB
    __hip_bfloat16* wpk2 = (__hip_bfloat16*)(ws + (512u << 10)); // 512 KB
    float*          cstp = (float*)(ws + (1024u << 10));         // 20 KB
    float*          w01p = (float*)(ws + (1044u << 10));         // 4 KB

    pack_w_kernel<<<512, 512, 0, stream>>>(W1, wpk1);
    pack_w_kernel<<<512, 512, 0, stream>>>(W2, wpk2);
    cstep_kernel<<<10, 512, 0, stream>>>(W0, b0, cstp);
    pack_w0_kernel<<<1, 512, 0, stream>>>(W0, w01p);
    flow_kernel<<<131072 / 16, 512, 0, stream>>>(x, w01p, cstp, wpk1, wpk2,
                                                 b1, b2, W3, b3, out);
}